// Round 5
// baseline (277.252 us; speedup 1.0000x reference)
//
#include <hip/hip_runtime.h>

#define N_NODES 50000
#define N_EDGES 800000
#define IN_C    256
#define HID_C   128
#define OUT_C   64

#define SCAN_CHUNK 512
#define SCAN_NB ((N_NODES + SCAN_CHUNK - 1) / SCAN_CHUNK)   // 98 (<= 256)

// ---------------------------------------------------------------- degree ---
__global__ void deg_kernel(const int* __restrict__ dst,
                           unsigned int* __restrict__ deg, int E) {
    int i = blockIdx.x * blockDim.x + threadIdx.x;
    if (i < E) {
        int d = dst[i];
        if ((unsigned)d < N_NODES) atomicAdd(&deg[d], 1u);
    }
}

// ------------------------------------------------------------------ scan ---
// Phase 1: per-block (512-elem chunk) exclusive scan + block sum.
// Fuses dinv = rsqrt(deg+1).
__global__ __launch_bounds__(256) void scan1_kernel(
        unsigned int* __restrict__ cur, unsigned int* __restrict__ bsum,
        float* __restrict__ dinv, int N) {
    __shared__ unsigned int lds[256];
    const int b = blockIdx.x;
    const int t = threadIdx.x;
    const int i0 = b * SCAN_CHUNK + 2 * t;

    unsigned e0 = (i0     < N) ? cur[i0]     : 0u;
    unsigned e1 = (i0 + 1 < N) ? cur[i0 + 1] : 0u;
    if (i0     < N) dinv[i0]     = rsqrtf((float)(e0 + 1u));
    if (i0 + 1 < N) dinv[i0 + 1] = rsqrtf((float)(e1 + 1u));

    unsigned p = e0 + e1;
    lds[t] = p;
    __syncthreads();
    for (int off = 1; off < 256; off <<= 1) {
        unsigned v = (t >= off) ? lds[t - off] : 0u;
        __syncthreads();
        lds[t] += v;
        __syncthreads();
    }
    unsigned excl = lds[t] - p;
    if (t == 255) bsum[b] = lds[255];
    if (i0     < N) cur[i0]     = excl;
    if (i0 + 1 < N) cur[i0 + 1] = excl + e0;
}

// Phase 2: block b adds sum(bsum[0..b)) to its chunk.
__global__ __launch_bounds__(256) void scan2_kernel(
        unsigned int* __restrict__ cur, const unsigned int* __restrict__ bsum,
        int N) {
    __shared__ unsigned int lds[256];
    const int b = blockIdx.x;
    const int t = threadIdx.x;
    lds[t] = (t < b && t < SCAN_NB) ? bsum[t] : 0u;
    __syncthreads();
    for (int off = 128; off > 0; off >>= 1) {
        if (t < off) lds[t] += lds[t + off];
        __syncthreads();
    }
    const unsigned offset = lds[0];
    const int i0 = b * SCAN_CHUNK + 2 * t;
    if (i0     < N) cur[i0]     += offset;
    if (i0 + 1 < N) cur[i0 + 1] += offset;
}

// ------------------------------------------------------------------ fill ---
__global__ void fill_kernel(const int* __restrict__ src,
                            const int* __restrict__ dst,
                            unsigned int* __restrict__ cur,
                            int* __restrict__ esrc, int E) {
    int i = blockIdx.x * blockDim.x + threadIdx.x;
    if (i < E) {
        int s = src[i];
        int d = dst[i];
        if ((unsigned)s >= N_NODES || (unsigned)d >= N_NODES) return;
        unsigned int pos = atomicAdd(&cur[d], 1u);
        esrc[pos] = s;
    }
}

// ------------------------------------------------------------------ GEMM ---
// Bank-conflict-free version:
//  - As padded [BK][BM+1]: transposed A-staging writes land ~2-way (free).
//  - Thread's TN cols split into TN/4 half-tiles at col = tx*4 + j4*(BN/2):
//    Bs reads are stride-4 (2-way, free), C stores coalesced per half-tile.
template <int BM, int BN, int BK, int TM, int TN, int KDIM, int NDIM>
__global__ __launch_bounds__(256) void gemm_kernel(
        const float* __restrict__ A, const float* __restrict__ B,
        float* __restrict__ C, int M) {
    __shared__ float As[BK][BM + 1];
    __shared__ float Bs[BK][BN];

    constexpr int TX = BN / TN;          // threads along N
    const int t  = threadIdx.x;
    const int tx = t % TX;
    const int ty = t / TX;               // (256/TX)*TM == BM
    const int block_row = blockIdx.x * BM;

    float acc[TM][TN] = {};

    for (int k0 = 0; k0 < KDIM; k0 += BK) {
        // stage A tile (BM x BK) transposed, float4 global loads
        for (int i = t; i < BM * BK / 4; i += 256) {
            int row = i / (BK / 4);
            int c4  = i % (BK / 4);
            int grow = block_row + row;
            if (grow >= M) grow = M - 1;
            float4 v = *(const float4*)&A[(size_t)grow * KDIM + k0 + c4 * 4];
            As[c4 * 4 + 0][row] = v.x;
            As[c4 * 4 + 1][row] = v.y;
            As[c4 * 4 + 2][row] = v.z;
            As[c4 * 4 + 3][row] = v.w;
        }
        // stage B tile (BK x BN)
        for (int i = t; i < BK * BN / 4; i += 256) {
            int row = i / (BN / 4);
            int c4  = i % (BN / 4);
            *(float4*)&Bs[row][c4 * 4] =
                *(const float4*)&B[(size_t)(k0 + row) * NDIM + c4 * 4];
        }
        __syncthreads();

#pragma unroll
        for (int kk = 0; kk < BK; ++kk) {
            float4 av = *(const float4*)&As[kk][ty * TM];   // TM == 4
            float a_[4] = {av.x, av.y, av.z, av.w};
            float4 bv[TN / 4];
#pragma unroll
            for (int j4 = 0; j4 < TN / 4; ++j4)
                bv[j4] = *(const float4*)&Bs[kk][tx * 4 + j4 * (BN / 2)];
#pragma unroll
            for (int i = 0; i < TM; ++i) {
                float ai = a_[i];
#pragma unroll
                for (int j4 = 0; j4 < TN / 4; ++j4) {
                    acc[i][j4 * 4 + 0] = fmaf(ai, bv[j4].x, acc[i][j4 * 4 + 0]);
                    acc[i][j4 * 4 + 1] = fmaf(ai, bv[j4].y, acc[i][j4 * 4 + 1]);
                    acc[i][j4 * 4 + 2] = fmaf(ai, bv[j4].z, acc[i][j4 * 4 + 2]);
                    acc[i][j4 * 4 + 3] = fmaf(ai, bv[j4].w, acc[i][j4 * 4 + 3]);
                }
            }
        }
        __syncthreads();
    }

#pragma unroll
    for (int i = 0; i < TM; ++i) {
        int grow = block_row + ty * TM + i;
        if (grow < M) {
#pragma unroll
            for (int j4 = 0; j4 < TN / 4; ++j4) {
                float4 v = {acc[i][j4 * 4 + 0], acc[i][j4 * 4 + 1],
                            acc[i][j4 * 4 + 2], acc[i][j4 * 4 + 3]};
                *(float4*)&C[(size_t)grow * NDIM + tx * 4 + j4 * (BN / 2)] = v;
            }
        }
    }
}

// ---------------------------------------------------------------- gather ---
// out[v] = dinv[v]*(sum_{s in in(v)} dinv[s]*h[s]) + dinv[v]^2*h[v] + bias
template <int C, bool RELU>
__global__ __launch_bounds__(256) void gather_kernel(
        const unsigned int* __restrict__ cur,   // ends after fill
        const int* __restrict__ esrc,
        const float* __restrict__ dinv,
        const float* __restrict__ h,
        const float* __restrict__ bias,
        float* __restrict__ out, int N) {
    constexpr int G = C / 4;
    int tid  = blockIdx.x * blockDim.x + threadIdx.x;
    int v    = tid / G;
    int lane = tid % G;
    if (v >= N) return;
    unsigned int start = (v == 0) ? 0u : cur[v - 1];
    unsigned int end   = cur[v];
    float4 acc = {0.f, 0.f, 0.f, 0.f};
    for (unsigned int e = start; e < end; ++e) {
        int s   = esrc[e];
        float w = dinv[s];
        float4 hv = *(const float4*)&h[(size_t)s * C + lane * 4];
        acc.x = fmaf(w, hv.x, acc.x);
        acc.y = fmaf(w, hv.y, acc.y);
        acc.z = fmaf(w, hv.z, acc.z);
        acc.w = fmaf(w, hv.w, acc.w);
    }
    float dv  = dinv[v];
    float dv2 = dv * dv;
    float4 hv = *(const float4*)&h[(size_t)v * C + lane * 4];
    float4 b  = *(const float4*)&bias[lane * 4];
    float4 r;
    r.x = fmaf(dv, acc.x, fmaf(dv2, hv.x, b.x));
    r.y = fmaf(dv, acc.y, fmaf(dv2, hv.y, b.y));
    r.z = fmaf(dv, acc.z, fmaf(dv2, hv.z, b.z));
    r.w = fmaf(dv, acc.w, fmaf(dv2, hv.w, b.w));
    if (RELU) {
        r.x = fmaxf(r.x, 0.f);
        r.y = fmaxf(r.y, 0.f);
        r.z = fmaxf(r.z, 0.f);
        r.w = fmaxf(r.w, 0.f);
    }
    *(float4*)&out[(size_t)v * C + lane * 4] = r;
}

// ------------------------------------------- fallback path (atomics) ------
template <int C, int C4>
__global__ void scatter_kernel(const int* __restrict__ src,
                               const int* __restrict__ dst,
                               const float* __restrict__ dinv,
                               const float* __restrict__ h,
                               float* __restrict__ out, int E) {
    int tid  = blockIdx.x * blockDim.x + threadIdx.x;
    int e    = tid / C4;
    int lane = tid % C4;
    if (e >= E) return;
    int s = src[e];
    int d = dst[e];
    if ((unsigned)s >= N_NODES || (unsigned)d >= N_NODES) return;
    float norm = dinv[s] * dinv[d];
    float4 v = *(const float4*)&h[(size_t)s * C + lane * 4];
    float* o = &out[(size_t)d * C + lane * 4];
    unsafeAtomicAdd(o + 0, v.x * norm);
    unsafeAtomicAdd(o + 1, v.y * norm);
    unsafeAtomicAdd(o + 2, v.z * norm);
    unsafeAtomicAdd(o + 3, v.w * norm);
}

__global__ void dinv_only_kernel(const unsigned int* __restrict__ deg,
                                 float* __restrict__ dinv, int N) {
    int i = blockIdx.x * blockDim.x + threadIdx.x;
    if (i < N) dinv[i] = rsqrtf((float)(deg[i] + 1u));
}

template <int C, bool RELU>
__global__ void epilogue_kernel(const float* __restrict__ agg,
                                const float* __restrict__ h,
                                const float* __restrict__ dinv,
                                const float* __restrict__ bias,
                                float* __restrict__ out, int N) {
    int tid = blockIdx.x * blockDim.x + threadIdx.x;
    int total = N * (C / 4);
    if (tid >= total) return;
    int c4  = tid % (C / 4);
    int row = tid / (C / 4);
    float d2 = dinv[row];
    d2 *= d2;
    float4 a  = *(const float4*)&agg[(size_t)tid * 4];
    float4 hv = *(const float4*)&h[(size_t)tid * 4];
    float4 b  = *(const float4*)&bias[c4 * 4];
    float4 r;
    r.x = a.x + hv.x * d2 + b.x;
    r.y = a.y + hv.y * d2 + b.y;
    r.z = a.z + hv.z * d2 + b.z;
    r.w = a.w + hv.w * d2 + b.w;
    if (RELU) {
        r.x = fmaxf(r.x, 0.f);
        r.y = fmaxf(r.y, 0.f);
        r.z = fmaxf(r.z, 0.f);
        r.w = fmaxf(r.w, 0.f);
    }
    *(float4*)&out[(size_t)tid * 4] = r;
}

// ---------------------------------------------------------------- launch ---
extern "C" void kernel_launch(void* const* d_in, const int* in_sizes, int n_in,
                              void* d_out, int out_size, void* d_ws, size_t ws_size,
                              hipStream_t stream) {
    const float* x   = (const float*)d_in[0];
    const int*   ei  = (const int*)d_in[1];
    const float* W1  = (const float*)d_in[2];
    const float* b1  = (const float*)d_in[3];
    const float* W2  = (const float*)d_in[4];
    const float* b2  = (const float*)d_in[5];
    float*       out = (float*)d_out;

    const int* src = ei;
    const int* dst = ei + N_EDGES;

    char* ws = (char*)d_ws;
    size_t off = 0;
    auto alloc = [&](size_t bytes) {
        void* p = ws + off;
        off += (bytes + 255) & ~(size_t)255;
        return p;
    };

    // --- CSR-gather path layout ---
    unsigned int* cur  = (unsigned int*)alloc(N_NODES * sizeof(unsigned int));
    unsigned int* bsum = (unsigned int*)alloc(SCAN_NB * sizeof(unsigned int));
    float*        dinv = (float*)alloc(N_NODES * sizeof(float));
    int*          esrc = (int*)alloc((size_t)N_EDGES * sizeof(int));
    float*        h1   = (float*)alloc((size_t)N_NODES * HID_C * sizeof(float));
    float*        g1   = (float*)alloc((size_t)N_NODES * HID_C * sizeof(float));
    float*        h2   = h1;
    size_t needed = off;

    if (ws_size >= needed) {
        hipMemsetAsync(cur, 0, N_NODES * sizeof(unsigned int), stream);

        deg_kernel<<<(N_EDGES + 255) / 256, 256, 0, stream>>>(dst, cur, N_EDGES);
        scan1_kernel<<<SCAN_NB, 256, 0, stream>>>(cur, bsum, dinv, N_NODES);
        scan2_kernel<<<SCAN_NB, 256, 0, stream>>>(cur, bsum, N_NODES);
        fill_kernel<<<(N_EDGES + 255) / 256, 256, 0, stream>>>(src, dst, cur,
                                                               esrc, N_EDGES);
        // layer 1
        gemm_kernel<64, 128, 32, 4, 8, IN_C, HID_C>
            <<<(N_NODES + 63) / 64, 256, 0, stream>>>(x, W1, h1, N_NODES);
        {
            int total = N_NODES * (HID_C / 4);
            gather_kernel<HID_C, true>
                <<<(total + 255) / 256, 256, 0, stream>>>(cur, esrc, dinv, h1,
                                                          b1, g1, N_NODES);
        }
        // layer 2
        gemm_kernel<64, 64, 32, 4, 4, HID_C, OUT_C>
            <<<(N_NODES + 63) / 64, 256, 0, stream>>>(g1, W2, h2, N_NODES);
        {
            int total = N_NODES * (OUT_C / 4);
            gather_kernel<OUT_C, false>
                <<<(total + 255) / 256, 256, 0, stream>>>(cur, esrc, dinv, h2,
                                                          b2, out, N_NODES);
        }
    } else {
        // ---------------- fallback: proven atomic-scatter path --------------
        off = 0;
        unsigned int* deg   = (unsigned int*)alloc(N_NODES * sizeof(unsigned int));
        float*        dinvF = (float*)alloc(N_NODES * sizeof(float));
        float*        h1F   = (float*)alloc((size_t)N_NODES * HID_C * sizeof(float));
        float*        agg1  = (float*)alloc((size_t)N_NODES * HID_C * sizeof(float));
        float*        h2F   = h1F;

        hipMemsetAsync(deg, 0, N_NODES * sizeof(unsigned int), stream);
        hipMemsetAsync(agg1, 0, (size_t)N_NODES * HID_C * sizeof(float), stream);
        hipMemsetAsync(out, 0, (size_t)N_NODES * OUT_C * sizeof(float), stream);

        deg_kernel<<<(N_EDGES + 255) / 256, 256, 0, stream>>>(dst, deg, N_EDGES);
        dinv_only_kernel<<<(N_NODES + 255) / 256, 256, 0, stream>>>(deg, dinvF,
                                                                    N_NODES);

        gemm_kernel<64, 128, 32, 4, 8, IN_C, HID_C>
            <<<(N_NODES + 63) / 64, 256, 0, stream>>>(x, W1, h1F, N_NODES);
        {
            long long total = (long long)N_EDGES * (HID_C / 4);
            scatter_kernel<HID_C, HID_C / 4>
                <<<(unsigned)((total + 255) / 256), 256, 0, stream>>>(
                    src, dst, dinvF, h1F, agg1, N_EDGES);
        }
        {
            int total = N_NODES * (HID_C / 4);
            epilogue_kernel<HID_C, true>
                <<<(total + 255) / 256, 256, 0, stream>>>(agg1, h1F, dinvF, b1,
                                                          agg1, N_NODES);
        }
        gemm_kernel<64, 64, 32, 4, 4, HID_C, OUT_C>
            <<<(N_NODES + 63) / 64, 256, 0, stream>>>(agg1, W2, h2F, N_NODES);
        {
            long long total = (long long)N_EDGES * (OUT_C / 4);
            scatter_kernel<OUT_C, OUT_C / 4>
                <<<(unsigned)((total + 255) / 256), 256, 0, stream>>>(
                    src, dst, dinvF, h2F, out, N_EDGES);
        }
        {
            int total = N_NODES * (OUT_C / 4);
            epilogue_kernel<OUT_C, false>
                <<<(total + 255) / 256, 256, 0, stream>>>(out, h2F, dinvF, b2,
                                                          out, N_NODES);
        }
    }
}

// Round 6
// 265.236 us; speedup vs baseline: 1.0453x; 1.0453x over previous
//
#include <hip/hip_runtime.h>

#define N_NODES 50000
#define N_EDGES 800000
#define IN_C    256
#define HID_C   128
#define OUT_C   64

#define SCAN_CHUNK 512
#define SCAN_NB ((N_NODES + SCAN_CHUNK - 1) / SCAN_CHUNK)   // 98 (<= 256)

// ----------------------------------------------------------- bf16 helpers --
__device__ __forceinline__ unsigned short f2bf(float f) {
    union { float f; unsigned int u; } c{f};
    unsigned int r = c.u + 0x7FFFu + ((c.u >> 16) & 1u);   // RNE
    return (unsigned short)(r >> 16);
}
__device__ __forceinline__ float bf2f(unsigned short b) {
    union { unsigned int u; float f; } c{(unsigned int)b << 16};
    return c.f;
}

// ---------------------------------------------------------------- degree ---
__global__ void deg_kernel(const int* __restrict__ dst,
                           unsigned int* __restrict__ deg, int E) {
    int i = blockIdx.x * blockDim.x + threadIdx.x;
    if (i < E) {
        int d = dst[i];
        if ((unsigned)d < N_NODES) atomicAdd(&deg[d], 1u);
    }
}

// ------------------------------------------------------------------ scan ---
__global__ __launch_bounds__(256) void scan1_kernel(
        unsigned int* __restrict__ cur, unsigned int* __restrict__ bsum,
        float* __restrict__ dinv, int N) {
    __shared__ unsigned int lds[256];
    const int b = blockIdx.x;
    const int t = threadIdx.x;
    const int i0 = b * SCAN_CHUNK + 2 * t;

    unsigned e0 = (i0     < N) ? cur[i0]     : 0u;
    unsigned e1 = (i0 + 1 < N) ? cur[i0 + 1] : 0u;
    if (i0     < N) dinv[i0]     = rsqrtf((float)(e0 + 1u));
    if (i0 + 1 < N) dinv[i0 + 1] = rsqrtf((float)(e1 + 1u));

    unsigned p = e0 + e1;
    lds[t] = p;
    __syncthreads();
    for (int off = 1; off < 256; off <<= 1) {
        unsigned v = (t >= off) ? lds[t - off] : 0u;
        __syncthreads();
        lds[t] += v;
        __syncthreads();
    }
    unsigned excl = lds[t] - p;
    if (t == 255) bsum[b] = lds[255];
    if (i0     < N) cur[i0]     = excl;
    if (i0 + 1 < N) cur[i0 + 1] = excl + e0;
}

__global__ __launch_bounds__(256) void scan2_kernel(
        unsigned int* __restrict__ cur, const unsigned int* __restrict__ bsum,
        int N) {
    __shared__ unsigned int lds[256];
    const int b = blockIdx.x;
    const int t = threadIdx.x;
    lds[t] = (t < b && t < SCAN_NB) ? bsum[t] : 0u;
    __syncthreads();
    for (int off = 128; off > 0; off >>= 1) {
        if (t < off) lds[t] += lds[t + off];
        __syncthreads();
    }
    const unsigned offset = lds[0];
    const int i0 = b * SCAN_CHUNK + 2 * t;
    if (i0     < N) cur[i0]     += offset;
    if (i0 + 1 < N) cur[i0 + 1] += offset;
}

// ------------------------------------------------------------------ fill ---
__global__ void fill_kernel(const int* __restrict__ src,
                            const int* __restrict__ dst,
                            unsigned int* __restrict__ cur,
                            int* __restrict__ esrc, int E) {
    int i = blockIdx.x * blockDim.x + threadIdx.x;
    if (i < E) {
        int s = src[i];
        int d = dst[i];
        if ((unsigned)s >= N_NODES || (unsigned)d >= N_NODES) return;
        unsigned int pos = atomicAdd(&cur[d], 1u);
        esrc[pos] = s;
    }
}

// ------------------------------------------------------------------ GEMM ---
// fp32 compute; output written as bf16 (BF16OUT=1) or fp32.
// As padded [BK][BM+1]; per-thread cols = two 4-wide half-tiles (conflict-free).
template <int BM, int BN, int BK, int TM, int TN, int KDIM, int NDIM, bool BF16OUT>
__global__ __launch_bounds__(256) void gemm_kernel(
        const float* __restrict__ A, const float* __restrict__ B,
        void* __restrict__ Cout, int M) {
    __shared__ float As[BK][BM + 1];
    __shared__ float Bs[BK][BN];

    constexpr int TX = BN / TN;
    const int t  = threadIdx.x;
    const int tx = t % TX;
    const int ty = t / TX;
    const int block_row = blockIdx.x * BM;

    float acc[TM][TN] = {};

    for (int k0 = 0; k0 < KDIM; k0 += BK) {
        for (int i = t; i < BM * BK / 4; i += 256) {
            int row = i / (BK / 4);
            int c4  = i % (BK / 4);
            int grow = block_row + row;
            if (grow >= M) grow = M - 1;
            float4 v = *(const float4*)&A[(size_t)grow * KDIM + k0 + c4 * 4];
            As[c4 * 4 + 0][row] = v.x;
            As[c4 * 4 + 1][row] = v.y;
            As[c4 * 4 + 2][row] = v.z;
            As[c4 * 4 + 3][row] = v.w;
        }
        for (int i = t; i < BK * BN / 4; i += 256) {
            int row = i / (BN / 4);
            int c4  = i % (BN / 4);
            *(float4*)&Bs[row][c4 * 4] =
                *(const float4*)&B[(size_t)(k0 + row) * NDIM + c4 * 4];
        }
        __syncthreads();

#pragma unroll
        for (int kk = 0; kk < BK; ++kk) {
            float4 av = *(const float4*)&As[kk][ty * TM];   // TM == 4
            float a_[4] = {av.x, av.y, av.z, av.w};
            float4 bv[TN / 4];
#pragma unroll
            for (int j4 = 0; j4 < TN / 4; ++j4)
                bv[j4] = *(const float4*)&Bs[kk][tx * 4 + j4 * (BN / 2)];
#pragma unroll
            for (int i = 0; i < TM; ++i) {
                float ai = a_[i];
#pragma unroll
                for (int j4 = 0; j4 < TN / 4; ++j4) {
                    acc[i][j4 * 4 + 0] = fmaf(ai, bv[j4].x, acc[i][j4 * 4 + 0]);
                    acc[i][j4 * 4 + 1] = fmaf(ai, bv[j4].y, acc[i][j4 * 4 + 1]);
                    acc[i][j4 * 4 + 2] = fmaf(ai, bv[j4].z, acc[i][j4 * 4 + 2]);
                    acc[i][j4 * 4 + 3] = fmaf(ai, bv[j4].w, acc[i][j4 * 4 + 3]);
                }
            }
        }
        __syncthreads();
    }

#pragma unroll
    for (int i = 0; i < TM; ++i) {
        int grow = block_row + ty * TM + i;
        if (grow < M) {
#pragma unroll
            for (int j4 = 0; j4 < TN / 4; ++j4) {
                size_t idx = (size_t)grow * NDIM + tx * 4 + j4 * (BN / 2);
                if (BF16OUT) {
                    ushort4 w = {f2bf(acc[i][j4 * 4 + 0]), f2bf(acc[i][j4 * 4 + 1]),
                                 f2bf(acc[i][j4 * 4 + 2]), f2bf(acc[i][j4 * 4 + 3])};
                    *(ushort4*)&((unsigned short*)Cout)[idx] = w;
                } else {
                    float4 v = {acc[i][j4 * 4 + 0], acc[i][j4 * 4 + 1],
                                acc[i][j4 * 4 + 2], acc[i][j4 * 4 + 3]};
                    *(float4*)&((float*)Cout)[idx] = v;
                }
            }
        }
    }
}

// ---------------------------------------------------------------- gather ---
// out[v] = dinv[v]*(sum_{s in in(v)} dinv[s]*h[s]) + dinv[v]^2*h[v] + bias
// h is bf16; accumulation fp32. G = C/4 lanes per node, ushort4 per lane.
template <int C, bool RELU>
__global__ __launch_bounds__(256) void gather_kernel(
        const unsigned int* __restrict__ cur,   // ends after fill
        const int* __restrict__ esrc,
        const float* __restrict__ dinv,
        const unsigned short* __restrict__ h,   // bf16
        const float* __restrict__ bias,
        float* __restrict__ out, int N) {
    constexpr int G = C / 4;
    int tid  = blockIdx.x * blockDim.x + threadIdx.x;
    int v    = tid / G;
    int lane = tid % G;
    if (v >= N) return;
    unsigned int start = (v == 0) ? 0u : cur[v - 1];
    unsigned int end   = cur[v];
    float4 acc = {0.f, 0.f, 0.f, 0.f};
    for (unsigned int e = start; e < end; ++e) {
        int s   = esrc[e];
        float w = dinv[s];
        ushort4 hv = *(const ushort4*)&h[(size_t)s * C + lane * 4];
        acc.x = fmaf(w, bf2f(hv.x), acc.x);
        acc.y = fmaf(w, bf2f(hv.y), acc.y);
        acc.z = fmaf(w, bf2f(hv.z), acc.z);
        acc.w = fmaf(w, bf2f(hv.w), acc.w);
    }
    float dv  = dinv[v];
    float dv2 = dv * dv;
    ushort4 hv = *(const ushort4*)&h[(size_t)v * C + lane * 4];
    float4 b  = *(const float4*)&bias[lane * 4];
    float4 r;
    r.x = fmaf(dv, acc.x, fmaf(dv2, bf2f(hv.x), b.x));
    r.y = fmaf(dv, acc.y, fmaf(dv2, bf2f(hv.y), b.y));
    r.z = fmaf(dv, acc.z, fmaf(dv2, bf2f(hv.z), b.z));
    r.w = fmaf(dv, acc.w, fmaf(dv2, bf2f(hv.w), b.w));
    if (RELU) {
        r.x = fmaxf(r.x, 0.f);
        r.y = fmaxf(r.y, 0.f);
        r.z = fmaxf(r.z, 0.f);
        r.w = fmaxf(r.w, 0.f);
    }
    *(float4*)&out[(size_t)v * C + lane * 4] = r;
}

// ------------------------------------------- fallback path (atomics) ------
template <int C, int C4>
__global__ void scatter_kernel(const int* __restrict__ src,
                               const int* __restrict__ dst,
                               const float* __restrict__ dinv,
                               const float* __restrict__ h,
                               float* __restrict__ out, int E) {
    int tid  = blockIdx.x * blockDim.x + threadIdx.x;
    int e    = tid / C4;
    int lane = tid % C4;
    if (e >= E) return;
    int s = src[e];
    int d = dst[e];
    if ((unsigned)s >= N_NODES || (unsigned)d >= N_NODES) return;
    float norm = dinv[s] * dinv[d];
    float4 v = *(const float4*)&h[(size_t)s * C + lane * 4];
    float* o = &out[(size_t)d * C + lane * 4];
    unsafeAtomicAdd(o + 0, v.x * norm);
    unsafeAtomicAdd(o + 1, v.y * norm);
    unsafeAtomicAdd(o + 2, v.z * norm);
    unsafeAtomicAdd(o + 3, v.w * norm);
}

__global__ void dinv_only_kernel(const unsigned int* __restrict__ deg,
                                 float* __restrict__ dinv, int N) {
    int i = blockIdx.x * blockDim.x + threadIdx.x;
    if (i < N) dinv[i] = rsqrtf((float)(deg[i] + 1u));
}

template <int C, bool RELU>
__global__ void epilogue_kernel(const float* __restrict__ agg,
                                const float* __restrict__ h,
                                const float* __restrict__ dinv,
                                const float* __restrict__ bias,
                                float* __restrict__ out, int N) {
    int tid = blockIdx.x * blockDim.x + threadIdx.x;
    int total = N * (C / 4);
    if (tid >= total) return;
    int c4  = tid % (C / 4);
    int row = tid / (C / 4);
    float d2 = dinv[row];
    d2 *= d2;
    float4 a  = *(const float4*)&agg[(size_t)tid * 4];
    float4 hv = *(const float4*)&h[(size_t)tid * 4];
    float4 b  = *(const float4*)&bias[c4 * 4];
    float4 r;
    r.x = a.x + hv.x * d2 + b.x;
    r.y = a.y + hv.y * d2 + b.y;
    r.z = a.z + hv.z * d2 + b.z;
    r.w = a.w + hv.w * d2 + b.w;
    if (RELU) {
        r.x = fmaxf(r.x, 0.f);
        r.y = fmaxf(r.y, 0.f);
        r.z = fmaxf(r.z, 0.f);
        r.w = fmaxf(r.w, 0.f);
    }
    *(float4*)&out[(size_t)tid * 4] = r;
}

// ---------------------------------------------------------------- launch ---
extern "C" void kernel_launch(void* const* d_in, const int* in_sizes, int n_in,
                              void* d_out, int out_size, void* d_ws, size_t ws_size,
                              hipStream_t stream) {
    const float* x   = (const float*)d_in[0];
    const int*   ei  = (const int*)d_in[1];
    const float* W1  = (const float*)d_in[2];
    const float* b1  = (const float*)d_in[3];
    const float* W2  = (const float*)d_in[4];
    const float* b2  = (const float*)d_in[5];
    float*       out = (float*)d_out;

    const int* src = ei;
    const int* dst = ei + N_EDGES;

    char* ws = (char*)d_ws;
    size_t off = 0;
    auto alloc = [&](size_t bytes) {
        void* p = ws + off;
        off += (bytes + 255) & ~(size_t)255;
        return p;
    };

    // --- CSR-gather path layout ---
    unsigned int*   cur  = (unsigned int*)alloc(N_NODES * sizeof(unsigned int));
    unsigned int*   bsum = (unsigned int*)alloc(SCAN_NB * sizeof(unsigned int));
    float*          dinv = (float*)alloc(N_NODES * sizeof(float));
    int*            esrc = (int*)alloc((size_t)N_EDGES * sizeof(int));
    unsigned short* h1   = (unsigned short*)alloc((size_t)N_NODES * HID_C * 2); // bf16
    float*          g1   = (float*)alloc((size_t)N_NODES * HID_C * sizeof(float));
    unsigned short* h2   = h1;   // layer-2 bf16 GEMM output reuses h1's space
    size_t needed = off;

    if (ws_size >= needed) {
        hipMemsetAsync(cur, 0, N_NODES * sizeof(unsigned int), stream);

        deg_kernel<<<(N_EDGES + 255) / 256, 256, 0, stream>>>(dst, cur, N_EDGES);
        scan1_kernel<<<SCAN_NB, 256, 0, stream>>>(cur, bsum, dinv, N_NODES);
        scan2_kernel<<<SCAN_NB, 256, 0, stream>>>(cur, bsum, N_NODES);
        fill_kernel<<<(N_EDGES + 255) / 256, 256, 0, stream>>>(src, dst, cur,
                                                               esrc, N_EDGES);
        // layer 1
        gemm_kernel<64, 128, 32, 4, 8, IN_C, HID_C, true>
            <<<(N_NODES + 63) / 64, 256, 0, stream>>>(x, W1, h1, N_NODES);
        {
            int total = N_NODES * (HID_C / 4);
            gather_kernel<HID_C, true>
                <<<(total + 255) / 256, 256, 0, stream>>>(cur, esrc, dinv, h1,
                                                          b1, g1, N_NODES);
        }
        // layer 2
        gemm_kernel<64, 64, 32, 4, 4, HID_C, OUT_C, true>
            <<<(N_NODES + 63) / 64, 256, 0, stream>>>(g1, W2, h2, N_NODES);
        {
            int total = N_NODES * (OUT_C / 4);
            gather_kernel<OUT_C, false>
                <<<(total + 255) / 256, 256, 0, stream>>>(cur, esrc, dinv, h2,
                                                          b2, out, N_NODES);
        }
    } else {
        // ---------------- fallback: proven atomic-scatter path --------------
        off = 0;
        unsigned int* deg   = (unsigned int*)alloc(N_NODES * sizeof(unsigned int));
        float*        dinvF = (float*)alloc(N_NODES * sizeof(float));
        float*        h1F   = (float*)alloc((size_t)N_NODES * HID_C * sizeof(float));
        float*        agg1  = (float*)alloc((size_t)N_NODES * HID_C * sizeof(float));
        float*        h2F   = h1F;

        hipMemsetAsync(deg, 0, N_NODES * sizeof(unsigned int), stream);
        hipMemsetAsync(agg1, 0, (size_t)N_NODES * HID_C * sizeof(float), stream);
        hipMemsetAsync(out, 0, (size_t)N_NODES * OUT_C * sizeof(float), stream);

        deg_kernel<<<(N_EDGES + 255) / 256, 256, 0, stream>>>(dst, deg, N_EDGES);
        dinv_only_kernel<<<(N_NODES + 255) / 256, 256, 0, stream>>>(deg, dinvF,
                                                                    N_NODES);

        gemm_kernel<64, 128, 32, 4, 8, IN_C, HID_C, false>
            <<<(N_NODES + 63) / 64, 256, 0, stream>>>(x, W1, h1F, N_NODES);
        {
            long long total = (long long)N_EDGES * (HID_C / 4);
            scatter_kernel<HID_C, HID_C / 4>
                <<<(unsigned)((total + 255) / 256), 256, 0, stream>>>(
                    src, dst, dinvF, h1F, agg1, N_EDGES);
        }
        {
            int total = N_NODES * (HID_C / 4);
            epilogue_kernel<HID_C, true>
                <<<(total + 255) / 256, 256, 0, stream>>>(agg1, h1F, dinvF, b1,
                                                          agg1, N_NODES);
        }
        gemm_kernel<64, 64, 32, 4, 4, HID_C, OUT_C, false>
            <<<(N_NODES + 63) / 64, 256, 0, stream>>>(agg1, W2, h2F, N_NODES);
        {
            long long total = (long long)N_EDGES * (OUT_C / 4);
            scatter_kernel<OUT_C, OUT_C / 4>
                <<<(unsigned)((total + 255) / 256), 256, 0, stream>>>(
                    src, dst, dinvF, h2F, out, N_EDGES);
        }
        {
            int total = N_NODES * (OUT_C / 4);
            epilogue_kernel<OUT_C, false>
                <<<(total + 255) / 256, 256, 0, stream>>>(out, h2F, dinvF, b2,
                                                          out, N_NODES);
        }
    }
}

// Round 7
// 258.988 us; speedup vs baseline: 1.0705x; 1.0241x over previous
//
#include <hip/hip_runtime.h>

#define N_NODES 50000
#define N_EDGES 800000
#define IN_C    256
#define HID_C   128
#define OUT_C   64

#define SCAN_CHUNK 512
#define SCAN_NB ((N_NODES + SCAN_CHUNK - 1) / SCAN_CHUNK)   // 98 (<= 256)

// ----------------------------------------------------------- bf16 helpers --
__device__ __forceinline__ unsigned short f2bf(float f) {
    union { float f; unsigned int u; } c{f};
    unsigned int r = c.u + 0x7FFFu + ((c.u >> 16) & 1u);   // RNE
    return (unsigned short)(r >> 16);
}
__device__ __forceinline__ float bf2f(unsigned short b) {
    union { unsigned int u; float f; } c{(unsigned int)b << 16};
    return c.f;
}

// ---------------------------------------------------------------- degree ---
__global__ void deg_kernel(const int* __restrict__ dst,
                           unsigned int* __restrict__ deg, int E) {
    int i = blockIdx.x * blockDim.x + threadIdx.x;
    if (i < E) {
        int d = dst[i];
        if ((unsigned)d < N_NODES) atomicAdd(&deg[d], 1u);
    }
}

// ------------------------------------------------------------------ scan ---
__global__ __launch_bounds__(256) void scan1_kernel(
        unsigned int* __restrict__ cur, unsigned int* __restrict__ bsum,
        float* __restrict__ dinv, int N) {
    __shared__ unsigned int lds[256];
    const int b = blockIdx.x;
    const int t = threadIdx.x;
    const int i0 = b * SCAN_CHUNK + 2 * t;

    unsigned e0 = (i0     < N) ? cur[i0]     : 0u;
    unsigned e1 = (i0 + 1 < N) ? cur[i0 + 1] : 0u;
    if (i0     < N) dinv[i0]     = rsqrtf((float)(e0 + 1u));
    if (i0 + 1 < N) dinv[i0 + 1] = rsqrtf((float)(e1 + 1u));

    unsigned p = e0 + e1;
    lds[t] = p;
    __syncthreads();
    for (int off = 1; off < 256; off <<= 1) {
        unsigned v = (t >= off) ? lds[t - off] : 0u;
        __syncthreads();
        lds[t] += v;
        __syncthreads();
    }
    unsigned excl = lds[t] - p;
    if (t == 255) bsum[b] = lds[255];
    if (i0     < N) cur[i0]     = excl;
    if (i0 + 1 < N) cur[i0 + 1] = excl + e0;
}

__global__ __launch_bounds__(256) void scan2_kernel(
        unsigned int* __restrict__ cur, const unsigned int* __restrict__ bsum,
        int N) {
    __shared__ unsigned int lds[256];
    const int b = blockIdx.x;
    const int t = threadIdx.x;
    lds[t] = (t < b && t < SCAN_NB) ? bsum[t] : 0u;
    __syncthreads();
    for (int off = 128; off > 0; off >>= 1) {
        if (t < off) lds[t] += lds[t + off];
        __syncthreads();
    }
    const unsigned offset = lds[0];
    const int i0 = b * SCAN_CHUNK + 2 * t;
    if (i0     < N) cur[i0]     += offset;
    if (i0 + 1 < N) cur[i0 + 1] += offset;
}

// ------------------------------------------------------------------ fill ---
__global__ void fill_kernel(const int* __restrict__ src,
                            const int* __restrict__ dst,
                            unsigned int* __restrict__ cur,
                            int* __restrict__ esrc, int E) {
    int i = blockIdx.x * blockDim.x + threadIdx.x;
    if (i < E) {
        int s = src[i];
        int d = dst[i];
        if ((unsigned)s >= N_NODES || (unsigned)d >= N_NODES) return;
        unsigned int pos = atomicAdd(&cur[d], 1u);
        esrc[pos] = s;
    }
}

// ------------------------------------------------------------------ GEMM ---
// fp32 compute; output written as bf16 (BF16OUT=1) or fp32.
// 2-D grid: blockIdx.y selects a BN-wide column panel (col_base).
// As padded [BK][BM+1]; B reads stride-4 (2-way, free); C stores coalesced.
template <int BM, int BN, int BK, int TM, int TN, int KDIM, int NDIM, bool BF16OUT>
__global__ __launch_bounds__(256) void gemm_kernel(
        const float* __restrict__ A, const float* __restrict__ B,
        void* __restrict__ Cout, int M) {
    __shared__ float As[BK][BM + 1];
    __shared__ float Bs[BK][BN];

    constexpr int TX = BN / TN;
    const int t  = threadIdx.x;
    const int tx = t % TX;
    const int ty = t / TX;
    const int block_row = blockIdx.x * BM;
    const int col_base  = blockIdx.y * BN;

    float acc[TM][TN] = {};

    for (int k0 = 0; k0 < KDIM; k0 += BK) {
        for (int i = t; i < BM * BK / 4; i += 256) {
            int row = i / (BK / 4);
            int c4  = i % (BK / 4);
            int grow = block_row + row;
            if (grow >= M) grow = M - 1;
            float4 v = *(const float4*)&A[(size_t)grow * KDIM + k0 + c4 * 4];
            As[c4 * 4 + 0][row] = v.x;
            As[c4 * 4 + 1][row] = v.y;
            As[c4 * 4 + 2][row] = v.z;
            As[c4 * 4 + 3][row] = v.w;
        }
        for (int i = t; i < BK * BN / 4; i += 256) {
            int row = i / (BN / 4);
            int c4  = i % (BN / 4);
            *(float4*)&Bs[row][c4 * 4] =
                *(const float4*)&B[(size_t)(k0 + row) * NDIM + col_base + c4 * 4];
        }
        __syncthreads();

#pragma unroll
        for (int kk = 0; kk < BK; ++kk) {
            float4 av = *(const float4*)&As[kk][ty * TM];   // TM == 4
            float a_[4] = {av.x, av.y, av.z, av.w};
            float4 bv[TN / 4];
#pragma unroll
            for (int j4 = 0; j4 < TN / 4; ++j4)
                bv[j4] = *(const float4*)&Bs[kk][tx * 4 + j4 * (BN / 2)];
#pragma unroll
            for (int i = 0; i < TM; ++i) {
                float ai = a_[i];
#pragma unroll
                for (int j4 = 0; j4 < TN / 4; ++j4) {
                    acc[i][j4 * 4 + 0] = fmaf(ai, bv[j4].x, acc[i][j4 * 4 + 0]);
                    acc[i][j4 * 4 + 1] = fmaf(ai, bv[j4].y, acc[i][j4 * 4 + 1]);
                    acc[i][j4 * 4 + 2] = fmaf(ai, bv[j4].z, acc[i][j4 * 4 + 2]);
                    acc[i][j4 * 4 + 3] = fmaf(ai, bv[j4].w, acc[i][j4 * 4 + 3]);
                }
            }
        }
        __syncthreads();
    }

#pragma unroll
    for (int i = 0; i < TM; ++i) {
        int grow = block_row + ty * TM + i;
        if (grow < M) {
#pragma unroll
            for (int j4 = 0; j4 < TN / 4; ++j4) {
                size_t idx = (size_t)grow * NDIM + col_base + tx * 4 + j4 * (BN / 2);
                if (BF16OUT) {
                    ushort4 w = {f2bf(acc[i][j4 * 4 + 0]), f2bf(acc[i][j4 * 4 + 1]),
                                 f2bf(acc[i][j4 * 4 + 2]), f2bf(acc[i][j4 * 4 + 3])};
                    *(ushort4*)&((unsigned short*)Cout)[idx] = w;
                } else {
                    float4 v = {acc[i][j4 * 4 + 0], acc[i][j4 * 4 + 1],
                                acc[i][j4 * 4 + 2], acc[i][j4 * 4 + 3]};
                    *(float4*)&((float*)Cout)[idx] = v;
                }
            }
        }
    }
}

// ---------------------------------------------------------------- gather ---
// out[v] = dinv[v]*(sum_{s in in(v)} dinv[s]*h[s]) + dinv[v]^2*h[v] + bias
// h is bf16; accumulation fp32. G = C/4 lanes per node, ushort4 per lane.
template <int C, bool RELU>
__global__ __launch_bounds__(256) void gather_kernel(
        const unsigned int* __restrict__ cur,   // ends after fill
        const int* __restrict__ esrc,
        const float* __restrict__ dinv,
        const unsigned short* __restrict__ h,   // bf16
        const float* __restrict__ bias,
        float* __restrict__ out, int N) {
    constexpr int G = C / 4;
    int tid  = blockIdx.x * blockDim.x + threadIdx.x;
    int v    = tid / G;
    int lane = tid % G;
    if (v >= N) return;
    unsigned int start = (v == 0) ? 0u : cur[v - 1];
    unsigned int end   = cur[v];
    float4 acc = {0.f, 0.f, 0.f, 0.f};
    for (unsigned int e = start; e < end; ++e) {
        int s   = esrc[e];
        float w = dinv[s];
        ushort4 hv = *(const ushort4*)&h[(size_t)s * C + lane * 4];
        acc.x = fmaf(w, bf2f(hv.x), acc.x);
        acc.y = fmaf(w, bf2f(hv.y), acc.y);
        acc.z = fmaf(w, bf2f(hv.z), acc.z);
        acc.w = fmaf(w, bf2f(hv.w), acc.w);
    }
    float dv  = dinv[v];
    float dv2 = dv * dv;
    ushort4 hv = *(const ushort4*)&h[(size_t)v * C + lane * 4];
    float4 b  = *(const float4*)&bias[lane * 4];
    float4 r;
    r.x = fmaf(dv, acc.x, fmaf(dv2, bf2f(hv.x), b.x));
    r.y = fmaf(dv, acc.y, fmaf(dv2, bf2f(hv.y), b.y));
    r.z = fmaf(dv, acc.z, fmaf(dv2, bf2f(hv.z), b.z));
    r.w = fmaf(dv, acc.w, fmaf(dv2, bf2f(hv.w), b.w));
    if (RELU) {
        r.x = fmaxf(r.x, 0.f);
        r.y = fmaxf(r.y, 0.f);
        r.z = fmaxf(r.z, 0.f);
        r.w = fmaxf(r.w, 0.f);
    }
    *(float4*)&out[(size_t)v * C + lane * 4] = r;
}

// ------------------------------------------- fallback path (atomics) ------
template <int C, int C4>
__global__ void scatter_kernel(const int* __restrict__ src,
                               const int* __restrict__ dst,
                               const float* __restrict__ dinv,
                               const float* __restrict__ h,
                               float* __restrict__ out, int E) {
    int tid  = blockIdx.x * blockDim.x + threadIdx.x;
    int e    = tid / C4;
    int lane = tid % C4;
    if (e >= E) return;
    int s = src[e];
    int d = dst[e];
    if ((unsigned)s >= N_NODES || (unsigned)d >= N_NODES) return;
    float norm = dinv[s] * dinv[d];
    float4 v = *(const float4*)&h[(size_t)s * C + lane * 4];
    float* o = &out[(size_t)d * C + lane * 4];
    unsafeAtomicAdd(o + 0, v.x * norm);
    unsafeAtomicAdd(o + 1, v.y * norm);
    unsafeAtomicAdd(o + 2, v.z * norm);
    unsafeAtomicAdd(o + 3, v.w * norm);
}

__global__ void dinv_only_kernel(const unsigned int* __restrict__ deg,
                                 float* __restrict__ dinv, int N) {
    int i = blockIdx.x * blockDim.x + threadIdx.x;
    if (i < N) dinv[i] = rsqrtf((float)(deg[i] + 1u));
}

template <int C, bool RELU>
__global__ void epilogue_kernel(const float* __restrict__ agg,
                                const float* __restrict__ h,
                                const float* __restrict__ dinv,
                                const float* __restrict__ bias,
                                float* __restrict__ out, int N) {
    int tid = blockIdx.x * blockDim.x + threadIdx.x;
    int total = N * (C / 4);
    if (tid >= total) return;
    int c4  = tid % (C / 4);
    int row = tid / (C / 4);
    float d2 = dinv[row];
    d2 *= d2;
    float4 a  = *(const float4*)&agg[(size_t)tid * 4];
    float4 hv = *(const float4*)&h[(size_t)tid * 4];
    float4 b  = *(const float4*)&bias[c4 * 4];
    float4 r;
    r.x = a.x + hv.x * d2 + b.x;
    r.y = a.y + hv.y * d2 + b.y;
    r.z = a.z + hv.z * d2 + b.z;
    r.w = a.w + hv.w * d2 + b.w;
    if (RELU) {
        r.x = fmaxf(r.x, 0.f);
        r.y = fmaxf(r.y, 0.f);
        r.z = fmaxf(r.z, 0.f);
        r.w = fmaxf(r.w, 0.f);
    }
    *(float4*)&out[(size_t)tid * 4] = r;
}

// ---------------------------------------------------------------- launch ---
extern "C" void kernel_launch(void* const* d_in, const int* in_sizes, int n_in,
                              void* d_out, int out_size, void* d_ws, size_t ws_size,
                              hipStream_t stream) {
    const float* x   = (const float*)d_in[0];
    const int*   ei  = (const int*)d_in[1];
    const float* W1  = (const float*)d_in[2];
    const float* b1  = (const float*)d_in[3];
    const float* W2  = (const float*)d_in[4];
    const float* b2  = (const float*)d_in[5];
    float*       out = (float*)d_out;

    const int* src = ei;
    const int* dst = ei + N_EDGES;

    char* ws = (char*)d_ws;
    size_t off = 0;
    auto alloc = [&](size_t bytes) {
        void* p = ws + off;
        off += (bytes + 255) & ~(size_t)255;
        return p;
    };

    // --- CSR-gather path layout ---
    unsigned int*   cur  = (unsigned int*)alloc(N_NODES * sizeof(unsigned int));
    unsigned int*   bsum = (unsigned int*)alloc(SCAN_NB * sizeof(unsigned int));
    float*          dinv = (float*)alloc(N_NODES * sizeof(float));
    int*            esrc = (int*)alloc((size_t)N_EDGES * sizeof(int));
    unsigned short* h1   = (unsigned short*)alloc((size_t)N_NODES * HID_C * 2); // bf16
    float*          g1   = (float*)alloc((size_t)N_NODES * HID_C * sizeof(float));
    unsigned short* h2   = h1;   // layer-2 bf16 GEMM output reuses h1's space
    size_t needed = off;

    if (ws_size >= needed) {
        hipMemsetAsync(cur, 0, N_NODES * sizeof(unsigned int), stream);

        deg_kernel<<<(N_EDGES + 255) / 256, 256, 0, stream>>>(dst, cur, N_EDGES);
        scan1_kernel<<<SCAN_NB, 256, 0, stream>>>(cur, bsum, dinv, N_NODES);
        scan2_kernel<<<SCAN_NB, 256, 0, stream>>>(cur, bsum, N_NODES);
        fill_kernel<<<(N_EDGES + 255) / 256, 256, 0, stream>>>(src, dst, cur,
                                                               esrc, N_EDGES);
        // layer 1: 64x64 tiles, 2-D grid (M/64 x 128/64) for occupancy
        gemm_kernel<64, 64, 32, 4, 4, IN_C, HID_C, true>
            <<<dim3((N_NODES + 63) / 64, HID_C / 64), 256, 0, stream>>>(
                x, W1, h1, N_NODES);
        {
            int total = N_NODES * (HID_C / 4);
            gather_kernel<HID_C, true>
                <<<(total + 255) / 256, 256, 0, stream>>>(cur, esrc, dinv, h1,
                                                          b1, g1, N_NODES);
        }
        // layer 2
        gemm_kernel<64, 64, 32, 4, 4, HID_C, OUT_C, true>
            <<<dim3((N_NODES + 63) / 64, OUT_C / 64), 256, 0, stream>>>(
                g1, W2, h2, N_NODES);
        {
            int total = N_NODES * (OUT_C / 4);
            gather_kernel<OUT_C, false>
                <<<(total + 255) / 256, 256, 0, stream>>>(cur, esrc, dinv, h2,
                                                          b2, out, N_NODES);
        }
    } else {
        // ---------------- fallback: proven atomic-scatter path --------------
        off = 0;
        unsigned int* deg   = (unsigned int*)alloc(N_NODES * sizeof(unsigned int));
        float*        dinvF = (float*)alloc(N_NODES * sizeof(float));
        float*        h1F   = (float*)alloc((size_t)N_NODES * HID_C * sizeof(float));
        float*        agg1  = (float*)alloc((size_t)N_NODES * HID_C * sizeof(float));
        float*        h2F   = h1F;

        hipMemsetAsync(deg, 0, N_NODES * sizeof(unsigned int), stream);
        hipMemsetAsync(agg1, 0, (size_t)N_NODES * HID_C * sizeof(float), stream);
        hipMemsetAsync(out, 0, (size_t)N_NODES * OUT_C * sizeof(float), stream);

        deg_kernel<<<(N_EDGES + 255) / 256, 256, 0, stream>>>(dst, deg, N_EDGES);
        dinv_only_kernel<<<(N_NODES + 255) / 256, 256, 0, stream>>>(deg, dinvF,
                                                                    N_NODES);

        gemm_kernel<64, 64, 32, 4, 4, IN_C, HID_C, false>
            <<<dim3((N_NODES + 63) / 64, HID_C / 64), 256, 0, stream>>>(
                x, W1, h1F, N_NODES);
        {
            long long total = (long long)N_EDGES * (HID_C / 4);
            scatter_kernel<HID_C, HID_C / 4>
                <<<(unsigned)((total + 255) / 256), 256, 0, stream>>>(
                    src, dst, dinvF, h1F, agg1, N_EDGES);
        }
        {
            int total = N_NODES * (HID_C / 4);
            epilogue_kernel<HID_C, true>
                <<<(total + 255) / 256, 256, 0, stream>>>(agg1, h1F, dinvF, b1,
                                                          agg1, N_NODES);
        }
        gemm_kernel<64, 64, 32, 4, 4, HID_C, OUT_C, false>
            <<<dim3((N_NODES + 63) / 64, OUT_C / 64), 256, 0, stream>>>(
                agg1, W2, h2F, N_NODES);
        {
            long long total = (long long)N_EDGES * (OUT_C / 4);
            scatter_kernel<OUT_C, OUT_C / 4>
                <<<(unsigned)((total + 255) / 256), 256, 0, stream>>>(
                    src, dst, dinvF, h2F, out, N_EDGES);
        }
        {
            int total = N_NODES * (OUT_C / 4);
            epilogue_kernel<OUT_C, false>
                <<<(total + 255) / 256, 256, 0, stream>>>(out, h2F, dinvF, b2,
                                                          out, N_NODES);
        }
    }
}